// Round 6
// baseline (491.806 us; speedup 1.0000x reference)
//
#include <hip/hip_runtime.h>
#include <math.h>

#define BK 10
#define KNODES 1024   // nodes per bucket
#define MAXNB 128     // max buckets (N <= 131072, src fits 17 bits)

typedef __attribute__((ext_vector_type(8))) short bf16x8;
typedef __attribute__((ext_vector_type(4))) float f32x4;

// ---- bf16 helpers ----------------------------------------------------------
__device__ __forceinline__ float bf2f(unsigned short u) {
  return __uint_as_float(((unsigned int)u) << 16);
}
__device__ __forceinline__ unsigned short f2bf(float f) {
  unsigned int i = __float_as_uint(f);
  unsigned int r = i + 0x7FFFu + ((i >> 16) & 1u);   // round-to-nearest-even
  return (unsigned short)(r >> 16);
}

// ---------------- W1 -> MFMA B-fragment layout, hi/lo bf16 split -------------
__global__ void w1frag_kernel(const float* __restrict__ W1,
                              unsigned short* __restrict__ whi,
                              unsigned short* __restrict__ wlo) {
  int b = blockIdx.x, lane = threadIdx.x;
  int kt = b >> 2, ct = b & 3;
  int n = lane & 15, g = lane >> 4;
  unsigned short hb[8], lb[8];
#pragma unroll
  for (int j = 0; j < 8; ++j) {
    int k = kt * 32 + g * 8 + j;
    float wv = W1[k * 64 + ct * 16 + n];
    unsigned short hi = f2bf(wv);
    float rem = wv - bf2f(hi);
    hb[j] = hi;
    lb[j] = f2bf(rem);
  }
  size_t base = ((size_t)b * 64 + lane) * 8;
  *(ushort4*)(whi + base)     = make_ushort4(hb[0], hb[1], hb[2], hb[3]);
  *(ushort4*)(whi + base + 4) = make_ushort4(hb[4], hb[5], hb[6], hb[7]);
  *(ushort4*)(wlo + base)     = make_ushort4(lb[0], lb[1], lb[2], lb[3]);
  *(ushort4*)(wlo + base + 4) = make_ushort4(lb[4], lb[5], lb[6], lb[7]);
}

// ---------------- GEMM1 via MFMA: h1b[N,64](bf16) = x[N,256] @ W1 ------------
__global__ __launch_bounds__(256) void gemm1_mfma_kernel(
    const float* __restrict__ x, const unsigned short* __restrict__ whi,
    const unsigned short* __restrict__ wlo, unsigned short* __restrict__ h1b, int N) {
  const int w = threadIdx.x >> 6, lane = threadIdx.x & 63;
  const int m = lane & 15, g = lane >> 4;
  const int rbase = blockIdx.x * 64 + w * 16;
  int arow = rbase + m;
  if (arow >= N) arow = N - 1;
  const float* xrow = x + (size_t)arow * 256 + g * 8;
  f32x4 acc[4] = {{0.f, 0.f, 0.f, 0.f}, {0.f, 0.f, 0.f, 0.f},
                  {0.f, 0.f, 0.f, 0.f}, {0.f, 0.f, 0.f, 0.f}};
#pragma unroll
  for (int kt = 0; kt < 8; ++kt) {
    float4 a0 = *(const float4*)(xrow + kt * 32);
    float4 a1 = *(const float4*)(xrow + kt * 32 + 4);
    float av[8] = {a0.x, a0.y, a0.z, a0.w, a1.x, a1.y, a1.z, a1.w};
    bf16x8 ahi, alo;
#pragma unroll
    for (int j = 0; j < 8; ++j) {
      unsigned int u = __float_as_uint(av[j]);
      unsigned short hi = (unsigned short)(u >> 16);      // truncate
      float rem = av[j] - bf2f(hi);
      ahi[j] = (short)hi;
      alo[j] = (short)(__float_as_uint(rem) >> 16);       // truncate residual
    }
    const unsigned short* wp = whi + ((size_t)(kt * 4) * 64 + lane) * 8;
    const unsigned short* lp = wlo + ((size_t)(kt * 4) * 64 + lane) * 8;
#pragma unroll
    for (int ct = 0; ct < 4; ++ct) {
      bf16x8 bh = *(const bf16x8*)(wp + (size_t)ct * 64 * 8);
      bf16x8 bl = *(const bf16x8*)(lp + (size_t)ct * 64 * 8);
      acc[ct] = __builtin_amdgcn_mfma_f32_16x16x32_bf16(ahi, bh, acc[ct], 0, 0, 0);
      acc[ct] = __builtin_amdgcn_mfma_f32_16x16x32_bf16(alo, bh, acc[ct], 0, 0, 0);
      acc[ct] = __builtin_amdgcn_mfma_f32_16x16x32_bf16(ahi, bl, acc[ct], 0, 0, 0);
    }
  }
#pragma unroll
  for (int r = 0; r < 4; ++r) {
    int ro = rbase + g * 4 + r;
    if (ro < N) {
#pragma unroll
      for (int ct = 0; ct < 4; ++ct)
        h1b[(size_t)ro * 64 + ct * 16 + m] = f2bf(acc[ct][r]);
    }
  }
}

// ---------------- s1[n,h] ----------------------------------------------------
__global__ void s1_kernel(const unsigned short* __restrict__ h1b,
                          const float* __restrict__ a_src,
                          const float* __restrict__ a_dst, float* __restrict__ s_src,
                          float* __restrict__ s_dst, int N8) {
  int id = blockIdx.x * blockDim.x + threadIdx.x;
  if (id >= N8) return;
  int h = id & 7;
  uint4 raw = *(const uint4*)(h1b + (size_t)id * 8);
  float hv[8];
  hv[0] = bf2f(raw.x & 0xffff); hv[1] = bf2f(raw.x >> 16);
  hv[2] = bf2f(raw.y & 0xffff); hv[3] = bf2f(raw.y >> 16);
  hv[4] = bf2f(raw.z & 0xffff); hv[5] = bf2f(raw.z >> 16);
  hv[6] = bf2f(raw.w & 0xffff); hv[7] = bf2f(raw.w >> 16);
  float ss = 0.f, sd = 0.f;
#pragma unroll
  for (int d = 0; d < 8; ++d) {
    ss = fmaf(hv[d], a_src[h * 8 + d], ss);
    sd = fmaf(hv[d], a_dst[h * 8 + d], sd);
  }
  s_src[id] = ss;
  s_dst[id] = sd;
}

// ---------------- sentinel init ---------------------------------------------
__global__ void init_sentinel_kernel(unsigned short* __restrict__ h1b,
                                     unsigned short* __restrict__ h2b,
                                     float* __restrict__ s1s, float* __restrict__ s2s,
                                     int NN) {
  int l = threadIdx.x;   // 64
  h1b[(size_t)NN * 64 + l] = 0;
  if (l < 40) h2b[(size_t)NN * 40 + l] = 0;
  if (l < 8)  s1s[(size_t)NN * 8 + l] = -1e30f;
  if (l == 0) s2s[NN] = -1e30f;
}

// ---------------- merged per-node count + bucket histogram -------------------
__global__ __launch_bounds__(256) void count_hist_kernel(const int* __restrict__ dst,
                                                         int* __restrict__ counts,
                                                         int* __restrict__ bcnt, int E, int NB) {
  __shared__ int h[MAXNB];
  int t = threadIdx.x;
  if (t < MAXNB) h[t] = 0;
  __syncthreads();
  for (int e = blockIdx.x * blockDim.x + t; e < E; e += gridDim.x * blockDim.x) {
    int d = dst[e];
    atomicAdd(&counts[d], 1);
    atomicAdd(&h[d >> BK], 1);
  }
  __syncthreads();
  if (t < NB && h[t]) atomicAdd(&bcnt[t], h[t]);
}

__global__ void bucket_scan_kernel(const int* __restrict__ bcnt, int* __restrict__ boff,
                                   int* __restrict__ bpos, int NB) {
  __shared__ int sm[MAXNB];
  int t = threadIdx.x;
  if (t < NB) sm[t] = bcnt[t];
  __syncthreads();
  if (t == 0) {
    int acc = 0;
    for (int b = 0; b < NB; ++b) { int c = sm[b]; sm[b] = acc; acc += c; }
  }
  __syncthreads();
  if (t < NB) { boff[t] = sm[t]; bpos[t] = sm[t]; }
}

// ---------------- bin edges into bucket-contiguous payload (no stage) --------
__global__ __launch_bounds__(256) void bin_kernel(const int* __restrict__ src,
                                                  const int* __restrict__ dst,
                                                  int* __restrict__ bpos,
                                                  unsigned int* __restrict__ payload,
                                                  int E, int NB) {
  __shared__ int hist[MAXNB], base[MAXNB], rnk[MAXNB];
  const int t = threadIdx.x;
  const int e0 = blockIdx.x * 2048;
  const int eend = min(e0 + 2048, E);
  if (t < MAXNB) { hist[t] = 0; rnk[t] = 0; }
  __syncthreads();
  for (int e = e0 + t; e < eend; e += 256) atomicAdd(&hist[dst[e] >> BK], 1);
  __syncthreads();
  if (t < NB) {
    int c = hist[t];
    base[t] = c ? atomicAdd(&bpos[t], c) : 0;
  }
  __syncthreads();
  for (int e = e0 + t; e < eend; e += 256) {
    int d = dst[e];
    int b = d >> BK;
    int r = atomicAdd(&rnk[b], 1);
    payload[base[b] + r] = (((unsigned)(d & (KNODES - 1))) << 17) | (unsigned)src[e];
  }
}

// counts padded to x4 inside the scan (aligned int4 col loads)
__global__ __launch_bounds__(1024) void scan_block_kernel(const int* __restrict__ counts,
                                                          int* __restrict__ tmp,
                                                          int* __restrict__ bsums, int N) {
  __shared__ int sm[1024];
  int t = threadIdx.x;
  int i = blockIdx.x * 1024 + t;
  int v = (i < N) ? ((counts[i] + 3) & ~3) : 0;
  sm[t] = v;
  __syncthreads();
  for (int off = 1; off < 1024; off <<= 1) {
    int u = (t >= off) ? sm[t - off] : 0;
    __syncthreads();
    sm[t] += u;
    __syncthreads();
  }
  if (i < N) tmp[i] = sm[t];
  if (t == 1023) bsums[blockIdx.x] = sm[1023];
}

__global__ void scan_sums_kernel(const int* __restrict__ bsums, int* __restrict__ boffs, int nb) {
  __shared__ int sm[128];
  int t = threadIdx.x;
  int v = (t < nb) ? bsums[t] : 0;
  sm[t] = v;
  __syncthreads();
  for (int off = 1; off < 128; off <<= 1) {
    int u = (t >= off) ? sm[t - off] : 0;
    __syncthreads();
    sm[t] += u;
    __syncthreads();
  }
  boffs[t] = sm[t] - v;
}

__global__ void finalize_kernel(const int* __restrict__ tmp, const int* __restrict__ boffs,
                                int* __restrict__ rowp, int N) {
  int i = blockIdx.x * blockDim.x + threadIdx.x;
  if (i < N) rowp[i + 1] = tmp[i] + boffs[i >> 10];
  if (i == 0) rowp[0] = 0;
}

// ---------------- fill col from payload (1024 thr, LDS cursors) --------------
__global__ __launch_bounds__(1024) void bucket_fill_kernel(const unsigned int* __restrict__ payload,
                                                           const int* __restrict__ boff,
                                                           const int* __restrict__ bcnt,
                                                           const int* __restrict__ rowp,
                                                           int* __restrict__ col, int NN) {
  __shared__ int pos[KNODES];
  int b = blockIdx.x, t = threadIdx.x;
  int n = (b << BK) + t;
  pos[t] = (n < NN) ? rowp[n] : 0;
  __syncthreads();
  int beg = boff[b], len = bcnt[b];
  for (int j = t; j < len; j += 1024) {
    unsigned int pay = payload[beg + j];
    int p = atomicAdd(&pos[pay >> 17], 1);
    col[p] = (int)(pay & 0x1FFFF);
  }
  __syncthreads();
  if (n < NN) {
    int endr = rowp[n + 1];
    for (int j = pos[t]; j < endr; ++j) col[j] = NN;   // sentinel pad to x4
  }
}

// ---------------- va[k] = sum_c W2[k,c] * a2[c] ------------------------------
__global__ void va_kernel(const float* __restrict__ W2, const float* __restrict__ a2s,
                          const float* __restrict__ a2d, float* __restrict__ vas,
                          float* __restrict__ vad) {
  int k = threadIdx.x;  // 64
  float s = 0.f, d = 0.f;
  for (int c = 0; c < 40; ++c) {
    float w = W2[k * 40 + c];
    s += w * a2s[c];
    d += w * a2d[c];
  }
  vas[k] = s;
  vad[k] = d;
}

// ---------------- layer-1 aggregation: lane-transposed scores, 4-edge blocks -
__global__ __launch_bounds__(256) void agg1_kernel(
    const int* __restrict__ rowp, const int* __restrict__ col,
    const float* __restrict__ s_src, const float* __restrict__ s_dst,
    const unsigned short* __restrict__ h1b, const float* __restrict__ b1,
    const float* __restrict__ vas, const float* __restrict__ vad,
    unsigned short* __restrict__ helub, float* __restrict__ s2s,
    float* __restrict__ s2d, int N) {
  int wv = threadIdx.x >> 6;
  int l  = threadIdx.x & 63;
  int n  = blockIdx.x * 4 + wv;
  if (n >= N) return;
  const int q  = l >> 3;          // edge slot (0..7; only q<4 active for scores)
  const int hh = l & 7;           // head for score stream
  const float sdq = s_dst[n * 8 + hh];
  const int beg = rowp[n], end = rowp[n + 1];
  float z = 0.f, acc = 0.f;
  for (int e = beg; e < end; e += 4) {
    int4 ia = *(const int4*)(col + e);
    int sel = q & 3;
    int myidx = sel == 0 ? ia.x : sel == 1 ? ia.y : sel == 2 ? ia.z : ia.w;
    float pv = s_src[(unsigned)myidx * 8u + (unsigned)hh];
    float tt = pv + sdq;
    tt = fmaxf(tt, 0.2f * tt);               // leaky_relu(0.2)
    float w = (q < 4) ? __expf(tt) : 0.f;
    z += w;
    int idxs[4] = {ia.x, ia.y, ia.z, ia.w};
#pragma unroll
    for (int j = 0; j < 4; ++j) {
      float wj = __shfl(w, j * 8 + q, 64);   // w of (edge j, head l>>3)
      unsigned short g = h1b[(unsigned)idxs[j] * 64u + (unsigned)l];
      acc = fmaf(wj, bf2f(g), acc);
    }
  }
  z += __shfl_xor(z, 8); z += __shfl_xor(z, 16); z += __shfl_xor(z, 32);
  float zf = __shfl(z, 9 * q, 64);
  float v = acc / (zf + 1e-16f) + b1[l];
  v = v > 0.f ? v : (__expf(v) - 1.f);       // elu
  helub[(size_t)n * 64 + l] = f2bf(v);
  float ps = v * vas[l];
  float pd = v * vad[l];
  for (int off = 32; off > 0; off >>= 1) {
    ps += __shfl_xor(ps, off);
    pd += __shfl_xor(pd, off);
  }
  if (l == 0) { s2s[n] = ps; s2d[n] = pd; }
}

// ---------------- GEMM2: h2b[N,40](bf16) = helub[N,64] @ W2[64,40] ----------
__global__ __launch_bounds__(320) void gemm2_kernel(const unsigned short* __restrict__ heb,
                                                    const float* __restrict__ W2,
                                                    unsigned short* __restrict__ h2b, int N) {
  __shared__ float xs[64][132];
  __shared__ float ws[64][40];
  const int r0 = blockIdx.x * 128;
  const int t  = threadIdx.x;
  const int ty = t / 10;
  const int tx = t % 10;
  for (int idx = t; idx < 1024; idx += 320) {
    int row = idx >> 3;
    int k8  = (idx & 7) << 3;
    uint4 raw = make_uint4(0, 0, 0, 0);
    if (r0 + row < N) raw = *(const uint4*)(heb + (size_t)(r0 + row) * 64 + k8);
    xs[k8 + 0][row] = bf2f(raw.x & 0xffff); xs[k8 + 1][row] = bf2f(raw.x >> 16);
    xs[k8 + 2][row] = bf2f(raw.y & 0xffff); xs[k8 + 3][row] = bf2f(raw.y >> 16);
    xs[k8 + 4][row] = bf2f(raw.z & 0xffff); xs[k8 + 5][row] = bf2f(raw.z >> 16);
    xs[k8 + 6][row] = bf2f(raw.w & 0xffff); xs[k8 + 7][row] = bf2f(raw.w >> 16);
  }
  for (int idx = t; idx < 640; idx += 320) {
    int k  = idx / 10;
    int c4 = (idx % 10) << 2;
    *(float4*)(&ws[k][c4]) = *(const float4*)(W2 + k * 40 + c4);
  }
  __syncthreads();
  float acc[4][4] = {};
#pragma unroll 8
  for (int k = 0; k < 64; ++k) {
    float4 xa = *(const float4*)(&xs[k][ty << 2]);
    float4 wb = *(const float4*)(&ws[k][tx << 2]);
    float xv[4] = {xa.x, xa.y, xa.z, xa.w};
    float wv[4] = {wb.x, wb.y, wb.z, wb.w};
#pragma unroll
    for (int i = 0; i < 4; ++i)
#pragma unroll
      for (int j = 0; j < 4; ++j) acc[i][j] = fmaf(xv[i], wv[j], acc[i][j]);
  }
#pragma unroll
  for (int i = 0; i < 4; ++i) {
    int r = r0 + (ty << 2) + i;
    if (r < N) {
      ushort4 o;
      o.x = f2bf(acc[i][0]); o.y = f2bf(acc[i][1]);
      o.z = f2bf(acc[i][2]); o.w = f2bf(acc[i][3]);
      *(ushort4*)(h2b + (size_t)r * 40 + (tx << 2)) = o;
    }
  }
}

// ---------------- layer-2 aggregation + log_softmax (4-edge blocks) ----------
__global__ __launch_bounds__(256) void agg2_kernel(
    const int* __restrict__ rowp, const int* __restrict__ col,
    const float* __restrict__ s2s, const float* __restrict__ s2d,
    const unsigned short* __restrict__ h2b, const float* __restrict__ b2,
    float* __restrict__ out, int N) {
  int wv = threadIdx.x >> 6;
  int l  = threadIdx.x & 63;
  int n  = blockIdx.x * 4 + wv;
  if (n >= N) return;
  const int q = l >> 3;
  const bool act = (l < 40);
  const unsigned lc = act ? (unsigned)l : 0u;
  const float sdv = s2d[n];
  const int beg = rowp[n], end = rowp[n + 1];
  float z = 0.f, acc = 0.f;
  for (int e = beg; e < end; e += 4) {
    int4 ia = *(const int4*)(col + e);
    int sel = q & 3;
    int myidx = sel == 0 ? ia.x : sel == 1 ? ia.y : sel == 2 ? ia.z : ia.w;
    float pv = s2s[myidx];
    float tt = pv + sdv;
    tt = fmaxf(tt, 0.2f * tt);
    float w = (q < 4) ? __expf(tt) : 0.f;
    z += w;
    int idxs[4] = {ia.x, ia.y, ia.z, ia.w};
#pragma unroll
    for (int j = 0; j < 4; ++j) {
      float wj = __shfl(w, j * 8, 64);
      unsigned short g = h2b[(unsigned)idxs[j] * 40u + lc];
      acc = fmaf(wj, bf2f(g), acc);
    }
  }
  z += __shfl_xor(z, 8); z += __shfl_xor(z, 16); z += __shfl_xor(z, 32);  // all lanes: Z
  float v = act ? (acc / (z + 1e-16f) + b2[l]) : -1e30f;
  float m = v;
  for (int off = 32; off > 0; off >>= 1) m = fmaxf(m, __shfl_xor(m, off));
  float ex = act ? __expf(v - m) : 0.f;
  float s = ex;
  for (int off = 32; off > 0; off >>= 1) s += __shfl_xor(s, off);
  if (act) out[(size_t)n * 40 + l] = v - m - logf(s);
}

// ---------------- launch -----------------------------------------------------
extern "C" void kernel_launch(void* const* d_in, const int* in_sizes, int n_in,
                              void* d_out, int out_size, void* d_ws, size_t ws_size,
                              hipStream_t stream) {
  const float* x   = (const float*)d_in[0];
  const int*   ei  = (const int*)d_in[1];
  const float* W1  = (const float*)d_in[2];
  const float* a1s = (const float*)d_in[3];
  const float* a1d = (const float*)d_in[4];
  const float* b1  = (const float*)d_in[5];
  const float* W2  = (const float*)d_in[6];
  const float* a2s = (const float*)d_in[7];
  const float* a2d = (const float*)d_in[8];
  const float* b2  = (const float*)d_in[9];
  float* out = (float*)d_out;
  (void)n_in; (void)out_size; (void)ws_size;

  const int NN = in_sizes[0] / 256;
  const int E  = in_sizes[1] / 2;
  const int NB = (NN + KNODES - 1) >> BK;
  const int* esrc = ei;
  const int* edst = ei + E;

  char* p = (char*)d_ws;
  auto alloc = [&](size_t bytes) -> char* {
    char* q = p;
    p += (bytes + 255) & ~(size_t)255;
    return q;
  };
  unsigned short* h1b   = (unsigned short*)alloc((size_t)(NN + 1) * 64 * 2);
  unsigned short* helub = (unsigned short*)alloc((size_t)NN * 64 * 2);
  unsigned short* h2b   = (unsigned short*)alloc((size_t)(NN + 1) * 40 * 2);
  float* s1s  = (float*)alloc((size_t)(NN + 1) * 8 * 4);
  float* s1d  = (float*)alloc((size_t)NN * 8 * 4);
  float* s2s  = (float*)alloc((size_t)(NN + 1) * 4);
  float* s2d  = (float*)alloc((size_t)NN * 4);
  int*   cnts = (int*)alloc((size_t)NN * 4);
  int*   tmp  = (int*)alloc((size_t)NN * 4);
  int*   rowp = (int*)alloc((size_t)(NN + 1) * 4);
  int*   bsum = (int*)alloc(128 * 4);
  int*   boffs = (int*)alloc(128 * 4);
  int*   bcnt = (int*)alloc(MAXNB * 4);
  int*   boff = (int*)alloc(MAXNB * 4);
  int*   bpos = (int*)alloc(MAXNB * 4);
  unsigned int* payload = (unsigned int*)alloc((size_t)E * 4);
  int*   col  = (int*)alloc(((size_t)E + 8 * (size_t)NN + 64) * 4);
  float* vas  = (float*)alloc(64 * 4);
  float* vad  = (float*)alloc(64 * 4);
  unsigned short* w1hi = (unsigned short*)alloc(32 * 64 * 8 * 2);
  unsigned short* w1lo = (unsigned short*)alloc(32 * 64 * 8 * 2);

  hipMemsetAsync(bcnt, 0, MAXNB * 4, stream);
  hipMemsetAsync(cnts, 0, (size_t)NN * 4, stream);

  // CSR build (binned, write-combined, rows padded to x4 with sentinel NN)
  count_hist_kernel<<<512, 256, 0, stream>>>(edst, cnts, bcnt, E, NB);
  bucket_scan_kernel<<<1, 128, 0, stream>>>(bcnt, boff, bpos, NB);
  bin_kernel<<<(E + 2047) / 2048, 256, 0, stream>>>(esrc, edst, bpos, payload, E, NB);
  int nb = (NN + 1023) / 1024;
  scan_block_kernel<<<nb, 1024, 0, stream>>>(cnts, tmp, bsum, NN);
  scan_sums_kernel<<<1, 128, 0, stream>>>(bsum, boffs, nb);
  finalize_kernel<<<(NN + 255) / 256, 256, 0, stream>>>(tmp, boffs, rowp, NN);
  bucket_fill_kernel<<<NB, 1024, 0, stream>>>(payload, boff, bcnt, rowp, col, NN);

  // dense math + aggregations
  w1frag_kernel<<<32, 64, 0, stream>>>(W1, w1hi, w1lo);
  gemm1_mfma_kernel<<<(NN + 63) / 64, 256, 0, stream>>>(x, w1hi, w1lo, h1b, NN);
  s1_kernel<<<(NN * 8 + 255) / 256, 256, 0, stream>>>(h1b, a1s, a1d, s1s, s1d, NN * 8);
  init_sentinel_kernel<<<1, 64, 0, stream>>>(h1b, h2b, s1s, s2s, NN);
  va_kernel<<<1, 64, 0, stream>>>(W2, a2s, a2d, vas, vad);
  agg1_kernel<<<(NN + 3) / 4, 256, 0, stream>>>(rowp, col, s1s, s1d, h1b, b1, vas, vad,
                                                helub, s2s, s2d, NN);
  gemm2_kernel<<<(NN + 127) / 128, 320, 0, stream>>>(helub, W2, h2b, NN);
  agg2_kernel<<<(NN + 3) / 4, 256, 0, stream>>>(rowp, col, s2s, s2d, h2b, b2, out, NN);
}

// Round 7
// 402.709 us; speedup vs baseline: 1.2212x; 1.2212x over previous
//
#include <hip/hip_runtime.h>
#include <math.h>

#define BK 10
#define KNODES 1024   // nodes per bucket
#define MAXNB 128     // max buckets (N <= 131072, src fits 17 bits)

typedef __attribute__((ext_vector_type(8))) short bf16x8;
typedef __attribute__((ext_vector_type(4))) float f32x4;

// ---- bf16 helpers ----------------------------------------------------------
__device__ __forceinline__ float bf2f(unsigned short u) {
  return __uint_as_float(((unsigned int)u) << 16);
}
__device__ __forceinline__ unsigned short f2bf(float f) {
  unsigned int i = __float_as_uint(f);
  unsigned int r = i + 0x7FFFu + ((i >> 16) & 1u);   // round-to-nearest-even
  return (unsigned short)(r >> 16);
}

// ---------------- prep: bcnt zero + W1 frags + va + sentinels (1 launch) -----
__global__ __launch_bounds__(256) void prep_kernel(
    const float* __restrict__ W1, const float* __restrict__ W2,
    const float* __restrict__ a2s, const float* __restrict__ a2d,
    unsigned short* __restrict__ whi, unsigned short* __restrict__ wlo,
    float* __restrict__ vas, float* __restrict__ vad,
    unsigned short* __restrict__ h1b, unsigned short* __restrict__ h2b,
    float* __restrict__ s1s, float* __restrict__ s2s,
    int* __restrict__ bcnt, int NN) {
  const int blk = blockIdx.x, t = threadIdx.x;
  if (blk == 0 && t < MAXNB) bcnt[t] = 0;
  if (blk < 32) {
    if (t < 64) {
      // W1 -> MFMA B-frag layout, hi/lo bf16 split. tile b=kt*4+ct
      int b = blk, lane = t;
      int kt = b >> 2, ct = b & 3;
      int n = lane & 15, g = lane >> 4;
      unsigned short hb[8], lb[8];
#pragma unroll
      for (int j = 0; j < 8; ++j) {
        int k = kt * 32 + g * 8 + j;
        float wv = W1[k * 64 + ct * 16 + n];
        unsigned short hi = f2bf(wv);
        float rem = wv - bf2f(hi);
        hb[j] = hi;
        lb[j] = f2bf(rem);
      }
      size_t base = ((size_t)b * 64 + lane) * 8;
      *(ushort4*)(whi + base)     = make_ushort4(hb[0], hb[1], hb[2], hb[3]);
      *(ushort4*)(whi + base + 4) = make_ushort4(hb[4], hb[5], hb[6], hb[7]);
      *(ushort4*)(wlo + base)     = make_ushort4(lb[0], lb[1], lb[2], lb[3]);
      *(ushort4*)(wlo + base + 4) = make_ushort4(lb[4], lb[5], lb[6], lb[7]);
    }
  } else if (blk == 32) {
    if (t < 64) {
      float s = 0.f, d = 0.f;
      for (int c = 0; c < 40; ++c) {
        float w = W2[t * 40 + c];
        s += w * a2s[c];
        d += w * a2d[c];
      }
      vas[t] = s;
      vad[t] = d;
    }
  } else if (blk == 33) {
    if (t < 64) {
      h1b[(size_t)NN * 64 + t] = 0;
      if (t < 40) h2b[(size_t)NN * 40 + t] = 0;
      if (t < 8)  s1s[(size_t)NN * 8 + t] = -1e30f;
      if (t == 0) s2s[NN] = -1e30f;
    }
  }
}

// ---------------- GEMM1 via MFMA: h1b[N,64](bf16) = x[N,256] @ W1 ------------
__global__ __launch_bounds__(256) void gemm1_mfma_kernel(
    const float* __restrict__ x, const unsigned short* __restrict__ whi,
    const unsigned short* __restrict__ wlo, unsigned short* __restrict__ h1b, int N) {
  const int w = threadIdx.x >> 6, lane = threadIdx.x & 63;
  const int m = lane & 15, g = lane >> 4;
  const int rbase = blockIdx.x * 64 + w * 16;
  int arow = rbase + m;
  if (arow >= N) arow = N - 1;
  const float* xrow = x + (size_t)arow * 256 + g * 8;
  f32x4 acc[4] = {{0.f, 0.f, 0.f, 0.f}, {0.f, 0.f, 0.f, 0.f},
                  {0.f, 0.f, 0.f, 0.f}, {0.f, 0.f, 0.f, 0.f}};
#pragma unroll
  for (int kt = 0; kt < 8; ++kt) {
    float4 a0 = *(const float4*)(xrow + kt * 32);
    float4 a1 = *(const float4*)(xrow + kt * 32 + 4);
    float av[8] = {a0.x, a0.y, a0.z, a0.w, a1.x, a1.y, a1.z, a1.w};
    bf16x8 ahi, alo;
#pragma unroll
    for (int j = 0; j < 8; ++j) {
      unsigned int u = __float_as_uint(av[j]);
      unsigned short hi = (unsigned short)(u >> 16);      // truncate
      float rem = av[j] - bf2f(hi);
      ahi[j] = (short)hi;
      alo[j] = (short)(__float_as_uint(rem) >> 16);       // truncate residual
    }
    const unsigned short* wp = whi + ((size_t)(kt * 4) * 64 + lane) * 8;
    const unsigned short* lp = wlo + ((size_t)(kt * 4) * 64 + lane) * 8;
#pragma unroll
    for (int ct = 0; ct < 4; ++ct) {
      bf16x8 bh = *(const bf16x8*)(wp + (size_t)ct * 64 * 8);
      bf16x8 bl = *(const bf16x8*)(lp + (size_t)ct * 64 * 8);
      acc[ct] = __builtin_amdgcn_mfma_f32_16x16x32_bf16(ahi, bh, acc[ct], 0, 0, 0);
      acc[ct] = __builtin_amdgcn_mfma_f32_16x16x32_bf16(alo, bh, acc[ct], 0, 0, 0);
      acc[ct] = __builtin_amdgcn_mfma_f32_16x16x32_bf16(ahi, bl, acc[ct], 0, 0, 0);
    }
  }
#pragma unroll
  for (int r = 0; r < 4; ++r) {
    int ro = rbase + g * 4 + r;
    if (ro < N) {
#pragma unroll
      for (int ct = 0; ct < 4; ++ct)
        h1b[(size_t)ro * 64 + ct * 16 + m] = f2bf(acc[ct][r]);
    }
  }
}

// ---------------- s1[n,h] ----------------------------------------------------
__global__ void s1_kernel(const unsigned short* __restrict__ h1b,
                          const float* __restrict__ a_src,
                          const float* __restrict__ a_dst, float* __restrict__ s_src,
                          float* __restrict__ s_dst, int N8) {
  int id = blockIdx.x * blockDim.x + threadIdx.x;
  if (id >= N8) return;
  int h = id & 7;
  uint4 raw = *(const uint4*)(h1b + (size_t)id * 8);
  float hv[8];
  hv[0] = bf2f(raw.x & 0xffff); hv[1] = bf2f(raw.x >> 16);
  hv[2] = bf2f(raw.y & 0xffff); hv[3] = bf2f(raw.y >> 16);
  hv[4] = bf2f(raw.z & 0xffff); hv[5] = bf2f(raw.z >> 16);
  hv[6] = bf2f(raw.w & 0xffff); hv[7] = bf2f(raw.w >> 16);
  float ss = 0.f, sd = 0.f;
#pragma unroll
  for (int d = 0; d < 8; ++d) {
    ss = fmaf(hv[d], a_src[h * 8 + d], ss);
    sd = fmaf(hv[d], a_dst[h * 8 + d], sd);
  }
  s_src[id] = ss;
  s_dst[id] = sd;
}

// ---------------- bucket histogram ------------------------------------------
__global__ __launch_bounds__(256) void bucket_hist_kernel(const int* __restrict__ dst,
                                                          int* __restrict__ bcnt, int E, int NB) {
  __shared__ int h[MAXNB];
  int t = threadIdx.x;
  if (t < MAXNB) h[t] = 0;
  __syncthreads();
  for (int e = blockIdx.x * blockDim.x + t; e < E; e += gridDim.x * blockDim.x)
    atomicAdd(&h[dst[e] >> BK], 1);
  __syncthreads();
  if (t < NB && h[t]) atomicAdd(&bcnt[t], h[t]);
}

// ---------------- bucket scan: payload offsets + slack col regions -----------
__global__ void bucket_scan_kernel(const int* __restrict__ bcnt, int* __restrict__ boffp,
                                   int* __restrict__ bpos, int* __restrict__ cbase, int NB) {
  __shared__ int sm[MAXNB], sc[MAXNB];
  int t = threadIdx.x;
  if (t < NB) { sm[t] = bcnt[t]; sc[t] = bcnt[t] + 8 * KNODES; }
  __syncthreads();
  if (t == 0) {
    int acc = 0, acc2 = 0;
    for (int b = 0; b < NB; ++b) {
      int c = sm[b]; sm[b] = acc; acc += c;
      int c2 = sc[b]; sc[b] = acc2; acc2 += c2;
    }
  }
  __syncthreads();
  if (t < NB) { boffp[t] = sm[t]; bpos[t] = sm[t]; cbase[t] = sc[t]; }
}

// ---------------- bin edges into bucket-contiguous payload (staged) ----------
__global__ __launch_bounds__(256) void bin_kernel(const int* __restrict__ src,
                                                  const int* __restrict__ dst,
                                                  int* __restrict__ bpos,
                                                  unsigned int* __restrict__ payload,
                                                  int E, int NB) {
  __shared__ int hist[MAXNB], soff[MAXNB], base[MAXNB], rnk[MAXNB];
  __shared__ unsigned int stage[8192];
  const int t = threadIdx.x;
  const int e0 = blockIdx.x * 8192;
  if (t < MAXNB) { hist[t] = 0; rnk[t] = 0; }
  __syncthreads();
  for (int j = t; j < 8192; j += 256) {
    int e = e0 + j;
    if (e < E) atomicAdd(&hist[dst[e] >> BK], 1);
  }
  __syncthreads();
  if (t == 0) {
    int acc = 0;
    for (int b = 0; b < NB; ++b) { soff[b] = acc; acc += hist[b]; }
  }
  __syncthreads();
  if (t < NB) {
    int c = hist[t];
    base[t] = c ? atomicAdd(&bpos[t], c) : 0;
  }
  __syncthreads();
  for (int j = t; j < 8192; j += 256) {
    int e = e0 + j;
    if (e < E) {
      int d = dst[e];
      int b = d >> BK;
      int s = src[e];
      int r = atomicAdd(&rnk[b], 1);
      stage[soff[b] + r] = (((unsigned)(d & (KNODES - 1))) << 17) | (unsigned)s;
    }
  }
  __syncthreads();
  int wave = t >> 6, lane = t & 63;
  for (int b = wave; b < NB; b += 4) {
    int len = hist[b], bs = soff[b], gb = base[b];
    for (int j = lane; j < len; j += 64) payload[gb + j] = stage[bs + j];
  }
}

// ---------------- fill2: count + padded scan + rbeg/rend + scatter + pad -----
// one block per bucket, 1024 threads; thread t owns node (b<<BK)+t
__global__ __launch_bounds__(1024) void fill2_kernel(const unsigned int* __restrict__ payload,
                                                     const int* __restrict__ boffp,
                                                     const int* __restrict__ bcnt,
                                                     const int* __restrict__ cbase,
                                                     int* __restrict__ col,
                                                     int* __restrict__ rbeg,
                                                     int* __restrict__ rend, int NN) {
  __shared__ int cnt[KNODES], scn[KNODES], pos[KNODES];
  const int b = blockIdx.x, t = threadIdx.x;
  cnt[t] = 0;
  __syncthreads();
  const int beg = boffp[b], len = bcnt[b];
  for (int j = t; j < len; j += 1024) atomicAdd(&cnt[payload[beg + j] >> 17], 1);
  __syncthreads();
  const int myc = cnt[t];
  const int padc = (myc + 7) & ~7;
  scn[t] = padc;
  __syncthreads();
  for (int off = 1; off < 1024; off <<= 1) {
    int v = (t >= off) ? scn[t - off] : 0;
    __syncthreads();
    scn[t] += v;
    __syncthreads();
  }
  const int mystart = cbase[b] + scn[t] - padc;   // exclusive scan
  const int n = (b << BK) + t;
  if (n < NN) { rbeg[n] = mystart; rend[n] = mystart + padc; }
  pos[t] = mystart;
  __syncthreads();
  for (int j = t; j < len; j += 1024) {
    unsigned int pay = payload[beg + j];
    int p = atomicAdd(&pos[pay >> 17], 1);
    col[p] = (int)(pay & 0x1FFFF);
  }
  __syncthreads();
  // sentinel-pad each row to padc (<=7 writes per node)
  for (int j = mystart + myc; j < mystart + padc; ++j) col[j] = NN;
}

// ---------------- layer-1 aggregation: lane-transposed scores, 8-edge blocks -
__global__ __launch_bounds__(256) void agg1_kernel(
    const int* __restrict__ rbeg, const int* __restrict__ rend,
    const int* __restrict__ col,
    const float* __restrict__ s_src, const float* __restrict__ s_dst,
    const unsigned short* __restrict__ h1b, const float* __restrict__ b1,
    const float* __restrict__ vas, const float* __restrict__ vad,
    unsigned short* __restrict__ helub, float* __restrict__ s2s,
    float* __restrict__ s2d, int N) {
  int wv = threadIdx.x >> 6;
  int l  = threadIdx.x & 63;
  int n  = blockIdx.x * 4 + wv;
  if (n >= N) return;
  const int q  = l >> 3;          // edge slot for score stream
  const int hh = l & 7;           // head for score stream
  const float sdq = s_dst[n * 8 + hh];
  const int beg = rbeg[n], end = rend[n];
  float z = 0.f, acc = 0.f;
  for (int e = beg; e < end; e += 8) {
    int4 ia = *(const int4*)(col + e);
    int4 ib = *(const int4*)(col + e + 4);
    int myidx = col[e + q];
    float pv = s_src[(unsigned)myidx * 8u + (unsigned)hh];
    float tt = pv + sdq;
    tt = fmaxf(tt, 0.2f * tt);               // leaky_relu(0.2)
    float w = __expf(tt);
    z += w;
    int idxs[8] = {ia.x, ia.y, ia.z, ia.w, ib.x, ib.y, ib.z, ib.w};
#pragma unroll
    for (int j = 0; j < 8; ++j) {
      float wj = __shfl(w, j * 8 + q, 64);   // w of (edge j, head l>>3)
      unsigned short g = h1b[(unsigned)idxs[j] * 64u + (unsigned)l];
      acc = fmaf(wj, bf2f(g), acc);
    }
  }
  z += __shfl_xor(z, 8); z += __shfl_xor(z, 16); z += __shfl_xor(z, 32);
  float zf = __shfl(z, 9 * q, 64);
  float v = acc / (zf + 1e-16f) + b1[l];
  v = v > 0.f ? v : (__expf(v) - 1.f);       // elu
  helub[(size_t)n * 64 + l] = f2bf(v);
  float ps = v * vas[l];
  float pd = v * vad[l];
  for (int off = 32; off > 0; off >>= 1) {
    ps += __shfl_xor(ps, off);
    pd += __shfl_xor(pd, off);
  }
  if (l == 0) { s2s[n] = ps; s2d[n] = pd; }
}

// ---------------- GEMM2: h2b[N,40](bf16) = helub[N,64] @ W2[64,40] ----------
__global__ __launch_bounds__(320) void gemm2_kernel(const unsigned short* __restrict__ heb,
                                                    const float* __restrict__ W2,
                                                    unsigned short* __restrict__ h2b, int N) {
  __shared__ float xs[64][132];
  __shared__ float ws[64][40];
  const int r0 = blockIdx.x * 128;
  const int t  = threadIdx.x;
  const int ty = t / 10;
  const int tx = t % 10;
  for (int idx = t; idx < 1024; idx += 320) {
    int row = idx >> 3;
    int k8  = (idx & 7) << 3;
    uint4 raw = make_uint4(0, 0, 0, 0);
    if (r0 + row < N) raw = *(const uint4*)(heb + (size_t)(r0 + row) * 64 + k8);
    xs[k8 + 0][row] = bf2f(raw.x & 0xffff); xs[k8 + 1][row] = bf2f(raw.x >> 16);
    xs[k8 + 2][row] = bf2f(raw.y & 0xffff); xs[k8 + 3][row] = bf2f(raw.y >> 16);
    xs[k8 + 4][row] = bf2f(raw.z & 0xffff); xs[k8 + 5][row] = bf2f(raw.z >> 16);
    xs[k8 + 6][row] = bf2f(raw.w & 0xffff); xs[k8 + 7][row] = bf2f(raw.w >> 16);
  }
  for (int idx = t; idx < 640; idx += 320) {
    int k  = idx / 10;
    int c4 = (idx % 10) << 2;
    *(float4*)(&ws[k][c4]) = *(const float4*)(W2 + k * 40 + c4);
  }
  __syncthreads();
  float acc[4][4] = {};
#pragma unroll 8
  for (int k = 0; k < 64; ++k) {
    float4 xa = *(const float4*)(&xs[k][ty << 2]);
    float4 wb = *(const float4*)(&ws[k][tx << 2]);
    float xv[4] = {xa.x, xa.y, xa.z, xa.w};
    float wv[4] = {wb.x, wb.y, wb.z, wb.w};
#pragma unroll
    for (int i = 0; i < 4; ++i)
#pragma unroll
      for (int j = 0; j < 4; ++j) acc[i][j] = fmaf(xv[i], wv[j], acc[i][j]);
  }
#pragma unroll
  for (int i = 0; i < 4; ++i) {
    int r = r0 + (ty << 2) + i;
    if (r < N) {
      ushort4 o;
      o.x = f2bf(acc[i][0]); o.y = f2bf(acc[i][1]);
      o.z = f2bf(acc[i][2]); o.w = f2bf(acc[i][3]);
      *(ushort4*)(h2b + (size_t)r * 40 + (tx << 2)) = o;
    }
  }
}

// ---------------- layer-2 aggregation + log_softmax (8-edge blocks) ----------
__global__ __launch_bounds__(256) void agg2_kernel(
    const int* __restrict__ rbeg, const int* __restrict__ rend,
    const int* __restrict__ col,
    const float* __restrict__ s2s, const float* __restrict__ s2d,
    const unsigned short* __restrict__ h2b, const float* __restrict__ b2,
    float* __restrict__ out, int N) {
  int wv = threadIdx.x >> 6;
  int l  = threadIdx.x & 63;
  int n  = blockIdx.x * 4 + wv;
  if (n >= N) return;
  const int q = l >> 3;
  const bool act = (l < 40);
  const unsigned lc = act ? (unsigned)l : 0u;
  const float sdv = s2d[n];
  const int beg = rbeg[n], end = rend[n];
  float z = 0.f, acc = 0.f;
  for (int e = beg; e < end; e += 8) {
    int4 ia = *(const int4*)(col + e);
    int4 ib = *(const int4*)(col + e + 4);
    int myidx = col[e + q];
    float pv = s2s[myidx];
    float tt = pv + sdv;
    tt = fmaxf(tt, 0.2f * tt);
    float w = __expf(tt);
    z += w;
    int idxs[8] = {ia.x, ia.y, ia.z, ia.w, ib.x, ib.y, ib.z, ib.w};
#pragma unroll
    for (int j = 0; j < 8; ++j) {
      float wj = __shfl(w, j * 8, 64);
      unsigned short g = h2b[(unsigned)idxs[j] * 40u + lc];
      acc = fmaf(wj, bf2f(g), acc);
    }
  }
  z += __shfl_xor(z, 8); z += __shfl_xor(z, 16); z += __shfl_xor(z, 32);  // all lanes: Z
  float v = act ? (acc / (z + 1e-16f) + b2[l]) : -1e30f;
  float m = v;
  for (int off = 32; off > 0; off >>= 1) m = fmaxf(m, __shfl_xor(m, off));
  float ex = act ? __expf(v - m) : 0.f;
  float s = ex;
  for (int off = 32; off > 0; off >>= 1) s += __shfl_xor(s, off);
  if (act) out[(size_t)n * 40 + l] = v - m - logf(s);
}

// ---------------- launch -----------------------------------------------------
extern "C" void kernel_launch(void* const* d_in, const int* in_sizes, int n_in,
                              void* d_out, int out_size, void* d_ws, size_t ws_size,
                              hipStream_t stream) {
  const float* x   = (const float*)d_in[0];
  const int*   ei  = (const int*)d_in[1];
  const float* W1  = (const float*)d_in[2];
  const float* a1s = (const float*)d_in[3];
  const float* a1d = (const float*)d_in[4];
  const float* b1  = (const float*)d_in[5];
  const float* W2  = (const float*)d_in[6];
  const float* a2s = (const float*)d_in[7];
  const float* a2d = (const float*)d_in[8];
  const float* b2  = (const float*)d_in[9];
  float* out = (float*)d_out;
  (void)n_in; (void)out_size; (void)ws_size;

  const int NN = in_sizes[0] / 256;
  const int E  = in_sizes[1] / 2;
  const int NB = (NN + KNODES - 1) >> BK;
  const int* esrc = ei;
  const int* edst = ei + E;

  char* p = (char*)d_ws;
  auto alloc = [&](size_t bytes) -> char* {
    char* q = p;
    p += (bytes + 255) & ~(size_t)255;
    return q;
  };
  unsigned short* h1b   = (unsigned short*)alloc((size_t)(NN + 1) * 64 * 2);
  unsigned short* helub = (unsigned short*)alloc((size_t)NN * 64 * 2);
  unsigned short* h2b   = (unsigned short*)alloc((size_t)(NN + 1) * 40 * 2);
  float* s1s  = (float*)alloc((size_t)(NN + 1) * 8 * 4);
  float* s1d  = (float*)alloc((size_t)NN * 8 * 4);
  float* s2s  = (float*)alloc((size_t)(NN + 1) * 4);
  float* s2d  = (float*)alloc((size_t)NN * 4);
  int*   rbeg = (int*)alloc((size_t)NN * 4);
  int*   rend = (int*)alloc((size_t)NN * 4);
  int*   bcnt = (int*)alloc(MAXNB * 4);
  int*   boffp = (int*)alloc(MAXNB * 4);
  int*   bpos = (int*)alloc(MAXNB * 4);
  int*   cbase = (int*)alloc(MAXNB * 4);
  unsigned int* payload = (unsigned int*)alloc((size_t)E * 4);
  int*   col  = (int*)alloc(((size_t)E + (size_t)8 * KNODES * MAXNB + 64) * 4);
  float* vas  = (float*)alloc(64 * 4);
  float* vad  = (float*)alloc(64 * 4);
  unsigned short* w1hi = (unsigned short*)alloc(32 * 64 * 8 * 2);
  unsigned short* w1lo = (unsigned short*)alloc(32 * 64 * 8 * 2);

  // 1) prep (bcnt zero, W1 frags, va, sentinels)
  prep_kernel<<<34, 256, 0, stream>>>(W1, W2, a2s, a2d, w1hi, w1lo, vas, vad,
                                      h1b, h2b, s1s, s2s, bcnt, NN);
  // 2-5) CSR build
  bucket_hist_kernel<<<512, 256, 0, stream>>>(edst, bcnt, E, NB);
  bucket_scan_kernel<<<1, 128, 0, stream>>>(bcnt, boffp, bpos, cbase, NB);
  bin_kernel<<<(E + 8191) / 8192, 256, 0, stream>>>(esrc, edst, bpos, payload, E, NB);
  fill2_kernel<<<NB, 1024, 0, stream>>>(payload, boffp, bcnt, cbase, col, rbeg, rend, NN);
  // 6-10) dense math + aggregations
  gemm1_mfma_kernel<<<(NN + 63) / 64, 256, 0, stream>>>(x, w1hi, w1lo, h1b, NN);
  s1_kernel<<<(NN * 8 + 255) / 256, 256, 0, stream>>>(h1b, a1s, a1d, s1s, s1d, NN * 8);
  agg1_kernel<<<(NN + 3) / 4, 256, 0, stream>>>(rbeg, rend, col, s1s, s1d, h1b, b1,
                                                vas, vad, helub, s2s, s2d, NN);
  gemm2_kernel<<<(NN + 127) / 128, 320, 0, stream>>>(helub, W2, h2b, NN);
  agg2_kernel<<<(NN + 3) / 4, 256, 0, stream>>>(rbeg, rend, col, s2s, s2d, h2b, b2, out, NN);
}

// Round 8
// 363.839 us; speedup vs baseline: 1.3517x; 1.1068x over previous
//
#include <hip/hip_runtime.h>
#include <math.h>

#define BK 10
#define KNODES 1024   // nodes per bucket
#define MAXNB 128     // max buckets (N <= 131072, src fits 17 bits)

typedef __attribute__((ext_vector_type(8))) short bf16x8;
typedef __attribute__((ext_vector_type(4))) float f32x4;

// ---- bf16 helpers ----------------------------------------------------------
__device__ __forceinline__ float bf2f(unsigned short u) {
  return __uint_as_float(((unsigned int)u) << 16);
}
__device__ __forceinline__ unsigned short f2bf(float f) {
  unsigned int i = __float_as_uint(f);
  unsigned int r = i + 0x7FFFu + ((i >> 16) & 1u);   // round-to-nearest-even
  return (unsigned short)(r >> 16);
}

// ---------------- prep: bpos init + W1 frags + va + sentinels (1 launch) -----
__global__ __launch_bounds__(256) void prep_kernel(
    const float* __restrict__ W1, const float* __restrict__ W2,
    const float* __restrict__ a2s, const float* __restrict__ a2d,
    unsigned short* __restrict__ whi, unsigned short* __restrict__ wlo,
    float* __restrict__ vas, float* __restrict__ vad,
    unsigned short* __restrict__ h1b, unsigned short* __restrict__ h2b,
    float* __restrict__ s1s, float* __restrict__ s2s,
    int* __restrict__ bpos, int capP, int NN) {
  const int blk = blockIdx.x, t = threadIdx.x;
  if (blk == 0 && t < MAXNB) bpos[t] = t * capP;
  if (blk < 32) {
    if (t < 64) {
      // W1 -> MFMA B-frag layout, hi/lo bf16 split. tile b=kt*4+ct
      int b = blk, lane = t;
      int kt = b >> 2, ct = b & 3;
      int n = lane & 15, g = lane >> 4;
      unsigned short hb[8], lb[8];
#pragma unroll
      for (int j = 0; j < 8; ++j) {
        int k = kt * 32 + g * 8 + j;
        float wv = W1[k * 64 + ct * 16 + n];
        unsigned short hi = f2bf(wv);
        float rem = wv - bf2f(hi);
        hb[j] = hi;
        lb[j] = f2bf(rem);
      }
      size_t base = ((size_t)b * 64 + lane) * 8;
      *(ushort4*)(whi + base)     = make_ushort4(hb[0], hb[1], hb[2], hb[3]);
      *(ushort4*)(whi + base + 4) = make_ushort4(hb[4], hb[5], hb[6], hb[7]);
      *(ushort4*)(wlo + base)     = make_ushort4(lb[0], lb[1], lb[2], lb[3]);
      *(ushort4*)(wlo + base + 4) = make_ushort4(lb[4], lb[5], lb[6], lb[7]);
    }
  } else if (blk == 32) {
    if (t < 64) {
      float s = 0.f, d = 0.f;
      for (int c = 0; c < 40; ++c) {
        float w = W2[t * 40 + c];
        s += w * a2s[c];
        d += w * a2d[c];
      }
      vas[t] = s;
      vad[t] = d;
    }
  } else if (blk == 33) {
    if (t < 64) {
      h1b[(size_t)NN * 64 + t] = 0;
      if (t < 40) h2b[(size_t)NN * 40 + t] = 0;
      if (t < 8)  s1s[(size_t)NN * 8 + t] = -1e30f;
      if (t == 0) s2s[NN] = -1e30f;
    }
  }
}

// ---------------- GEMM1 via MFMA: h1b[N,64](bf16) = x[N,256] @ W1 ------------
__global__ __launch_bounds__(256) void gemm1_mfma_kernel(
    const float* __restrict__ x, const unsigned short* __restrict__ whi,
    const unsigned short* __restrict__ wlo, unsigned short* __restrict__ h1b, int N) {
  const int w = threadIdx.x >> 6, lane = threadIdx.x & 63;
  const int m = lane & 15, g = lane >> 4;
  const int rbase = blockIdx.x * 64 + w * 16;
  int arow = rbase + m;
  if (arow >= N) arow = N - 1;
  const float* xrow = x + (size_t)arow * 256 + g * 8;
  f32x4 acc[4] = {{0.f, 0.f, 0.f, 0.f}, {0.f, 0.f, 0.f, 0.f},
                  {0.f, 0.f, 0.f, 0.f}, {0.f, 0.f, 0.f, 0.f}};
#pragma unroll
  for (int kt = 0; kt < 8; ++kt) {
    float4 a0 = *(const float4*)(xrow + kt * 32);
    float4 a1 = *(const float4*)(xrow + kt * 32 + 4);
    float av[8] = {a0.x, a0.y, a0.z, a0.w, a1.x, a1.y, a1.z, a1.w};
    bf16x8 ahi, alo;
#pragma unroll
    for (int j = 0; j < 8; ++j) {
      unsigned int u = __float_as_uint(av[j]);
      unsigned short hi = (unsigned short)(u >> 16);      // truncate
      float rem = av[j] - bf2f(hi);
      ahi[j] = (short)hi;
      alo[j] = (short)(__float_as_uint(rem) >> 16);       // truncate residual
    }
    const unsigned short* wp = whi + ((size_t)(kt * 4) * 64 + lane) * 8;
    const unsigned short* lp = wlo + ((size_t)(kt * 4) * 64 + lane) * 8;
#pragma unroll
    for (int ct = 0; ct < 4; ++ct) {
      bf16x8 bh = *(const bf16x8*)(wp + (size_t)ct * 64 * 8);
      bf16x8 bl = *(const bf16x8*)(lp + (size_t)ct * 64 * 8);
      acc[ct] = __builtin_amdgcn_mfma_f32_16x16x32_bf16(ahi, bh, acc[ct], 0, 0, 0);
      acc[ct] = __builtin_amdgcn_mfma_f32_16x16x32_bf16(alo, bh, acc[ct], 0, 0, 0);
      acc[ct] = __builtin_amdgcn_mfma_f32_16x16x32_bf16(ahi, bl, acc[ct], 0, 0, 0);
    }
  }
#pragma unroll
  for (int r = 0; r < 4; ++r) {
    int ro = rbase + g * 4 + r;
    if (ro < N) {
#pragma unroll
      for (int ct = 0; ct < 4; ++ct)
        h1b[(size_t)ro * 64 + ct * 16 + m] = f2bf(acc[ct][r]);
    }
  }
}

// ---------------- s1[n,h] ----------------------------------------------------
__global__ void s1_kernel(const unsigned short* __restrict__ h1b,
                          const float* __restrict__ a_src,
                          const float* __restrict__ a_dst, float* __restrict__ s_src,
                          float* __restrict__ s_dst, int N8) {
  int id = blockIdx.x * blockDim.x + threadIdx.x;
  if (id >= N8) return;
  int h = id & 7;
  uint4 raw = *(const uint4*)(h1b + (size_t)id * 8);
  float hv[8];
  hv[0] = bf2f(raw.x & 0xffff); hv[1] = bf2f(raw.x >> 16);
  hv[2] = bf2f(raw.y & 0xffff); hv[3] = bf2f(raw.y >> 16);
  hv[4] = bf2f(raw.z & 0xffff); hv[5] = bf2f(raw.z >> 16);
  hv[6] = bf2f(raw.w & 0xffff); hv[7] = bf2f(raw.w >> 16);
  float ss = 0.f, sd = 0.f;
#pragma unroll
  for (int d = 0; d < 8; ++d) {
    ss = fmaf(hv[d], a_src[h * 8 + d], ss);
    sd = fmaf(hv[d], a_dst[h * 8 + d], sd);
  }
  s_src[id] = ss;
  s_dst[id] = sd;
}

// ---------------- bin edges into fixed-capacity bucket regions (staged) ------
__global__ __launch_bounds__(256) void bin_kernel(const int* __restrict__ src,
                                                  const int* __restrict__ dst,
                                                  int* __restrict__ bpos,
                                                  unsigned int* __restrict__ payload,
                                                  int E, int NB, int capP) {
  __shared__ int hist[MAXNB], soff[MAXNB], base[MAXNB], rnk[MAXNB];
  __shared__ unsigned int stage[4096];
  const int t = threadIdx.x;
  const int e0 = blockIdx.x * 4096;
  if (t < MAXNB) { hist[t] = 0; rnk[t] = 0; }
  __syncthreads();
  for (int j = t; j < 4096; j += 256) {
    int e = e0 + j;
    if (e < E) atomicAdd(&hist[dst[e] >> BK], 1);
  }
  __syncthreads();
  if (t == 0) {
    int acc = 0;
    for (int b = 0; b < NB; ++b) { soff[b] = acc; acc += hist[b]; }
  }
  __syncthreads();
  if (t < NB) {
    int c = hist[t];
    base[t] = c ? atomicAdd(&bpos[t], c) : 0;
  }
  __syncthreads();
  for (int j = t; j < 4096; j += 256) {
    int e = e0 + j;
    if (e < E) {
      int d = dst[e];
      int b = d >> BK;
      int s = src[e];
      int r = atomicAdd(&rnk[b], 1);
      stage[soff[b] + r] = (((unsigned)(d & (KNODES - 1))) << 17) | (unsigned)s;
    }
  }
  __syncthreads();
  int wave = t >> 6, lane = t & 63;
  for (int b = wave; b < NB; b += 4) {
    int len = hist[b], bs = soff[b], gb = base[b];
    int lim = (b + 1) * capP;
    for (int j = lane; j < len; j += 64)
      if (gb + j < lim) payload[gb + j] = stage[bs + j];   // overflow guard
  }
}

// ---------------- fill2: count + padded scan + rbeg/rend + scatter + pad -----
__global__ __launch_bounds__(1024) void fill2_kernel(const unsigned int* __restrict__ payload,
                                                     const int* __restrict__ bpos,
                                                     int* __restrict__ col,
                                                     int* __restrict__ rbeg,
                                                     int* __restrict__ rend,
                                                     int capP, int NN) {
  __shared__ int cnt[KNODES], scn[KNODES], pos[KNODES];
  const int b = blockIdx.x, t = threadIdx.x;
  cnt[t] = 0;
  __syncthreads();
  const int beg = b * capP;
  int len = bpos[b] - beg;
  if (len > capP) len = capP;
  for (int j = t; j < len; j += 1024) atomicAdd(&cnt[payload[beg + j] >> 17], 1);
  __syncthreads();
  const int myc = cnt[t];
  const int padc = (myc + 7) & ~7;
  scn[t] = padc;
  __syncthreads();
  for (int off = 1; off < 1024; off <<= 1) {
    int v = (t >= off) ? scn[t - off] : 0;
    __syncthreads();
    scn[t] += v;
    __syncthreads();
  }
  const int mystart = b * (capP + 8 * KNODES) + scn[t] - padc;   // exclusive scan
  const int n = (b << BK) + t;
  if (n < NN) { rbeg[n] = mystart; rend[n] = mystart + padc; }
  pos[t] = mystart;
  __syncthreads();
  for (int j = t; j < len; j += 1024) {
    unsigned int pay = payload[beg + j];
    int p = atomicAdd(&pos[pay >> 17], 1);
    col[p] = (int)(pay & 0x1FFFF);
  }
  __syncthreads();
  // sentinel-pad each row to padc (<=7 writes per node)
  for (int j = mystart + myc; j < mystart + padc; ++j) col[j] = NN;
}

// ---------------- layer-1 aggregation: lane-transposed scores, 16-deep -------
__global__ __launch_bounds__(256) void agg1_kernel(
    const int* __restrict__ rbeg, const int* __restrict__ rend,
    const int* __restrict__ col,
    const float* __restrict__ s_src, const float* __restrict__ s_dst,
    const unsigned short* __restrict__ h1b, const float* __restrict__ b1,
    const float* __restrict__ vas, const float* __restrict__ vad,
    unsigned short* __restrict__ helub, float* __restrict__ s2s,
    float* __restrict__ s2d, int N) {
  int wv = threadIdx.x >> 6;
  int l  = threadIdx.x & 63;
  int n  = blockIdx.x * 4 + wv;
  if (n >= N) return;
  const int q  = l >> 3;          // edge slot for score stream
  const int hh = l & 7;           // head for score stream
  const float sdq = s_dst[n * 8 + hh];
  const int beg = __builtin_amdgcn_readfirstlane(rbeg[n]);
  const int end = __builtin_amdgcn_readfirstlane(rend[n]);
  float z = 0.f, acc = 0.f;
  int e = beg;
  if (((end - beg) >> 3) & 1) {   // odd 8-block first (wave-uniform branch)
    int4 ia = *(const int4*)(col + e);
    int4 ib = *(const int4*)(col + e + 4);
    int myidx = col[e + q];
    float pv = s_src[(unsigned)myidx * 8u + (unsigned)hh];
    float tt = pv + sdq;
    tt = fmaxf(tt, 0.2f * tt);
    float w = __expf(tt);
    z += w;
    int idxs[8] = {ia.x, ia.y, ia.z, ia.w, ib.x, ib.y, ib.z, ib.w};
#pragma unroll
    for (int j = 0; j < 8; ++j) {
      float wj = __shfl(w, j * 8 + q, 64);
      unsigned short g = h1b[(unsigned)idxs[j] * 64u + (unsigned)l];
      acc = fmaf(wj, bf2f(g), acc);
    }
    e += 8;
  }
  for (; e < end; e += 16) {
    int4 ia = *(const int4*)(col + e);
    int4 ib = *(const int4*)(col + e + 4);
    int4 ic = *(const int4*)(col + e + 8);
    int4 id = *(const int4*)(col + e + 12);
    int my0 = col[e + q];
    int my1 = col[e + 8 + q];
    float pv0 = s_src[(unsigned)my0 * 8u + (unsigned)hh];
    float pv1 = s_src[(unsigned)my1 * 8u + (unsigned)hh];
    int idxs[16] = {ia.x, ia.y, ia.z, ia.w, ib.x, ib.y, ib.z, ib.w,
                    ic.x, ic.y, ic.z, ic.w, id.x, id.y, id.z, id.w};
    unsigned short gg[16];
#pragma unroll
    for (int j = 0; j < 16; ++j) gg[j] = h1b[(unsigned)idxs[j] * 64u + (unsigned)l];
    float t0 = pv0 + sdq; t0 = fmaxf(t0, 0.2f * t0); float w0 = __expf(t0);
    float t1 = pv1 + sdq; t1 = fmaxf(t1, 0.2f * t1); float w1 = __expf(t1);
    z += w0 + w1;
#pragma unroll
    for (int j = 0; j < 8; ++j) {
      float wj = __shfl(w0, j * 8 + q, 64);
      acc = fmaf(wj, bf2f(gg[j]), acc);
    }
#pragma unroll
    for (int j = 0; j < 8; ++j) {
      float wj = __shfl(w1, j * 8 + q, 64);
      acc = fmaf(wj, bf2f(gg[8 + j]), acc);
    }
  }
  z += __shfl_xor(z, 8); z += __shfl_xor(z, 16); z += __shfl_xor(z, 32);
  float zf = __shfl(z, 9 * q, 64);
  float v = acc / (zf + 1e-16f) + b1[l];
  v = v > 0.f ? v : (__expf(v) - 1.f);       // elu
  helub[(size_t)n * 64 + l] = f2bf(v);
  float ps = v * vas[l];
  float pd = v * vad[l];
  for (int off = 32; off > 0; off >>= 1) {
    ps += __shfl_xor(ps, off);
    pd += __shfl_xor(pd, off);
  }
  if (l == 0) { s2s[n] = ps; s2d[n] = pd; }
}

// ---------------- GEMM2: h2b[N,40](bf16) = helub[N,64] @ W2[64,40] ----------
__global__ __launch_bounds__(320) void gemm2_kernel(const unsigned short* __restrict__ heb,
                                                    const float* __restrict__ W2,
                                                    unsigned short* __restrict__ h2b, int N) {
  __shared__ float xs[64][132];
  __shared__ float ws[64][40];
  const int r0 = blockIdx.x * 128;
  const int t  = threadIdx.x;
  const int ty = t / 10;
  const int tx = t % 10;
  for (int idx = t; idx < 1024; idx += 320) {
    int row = idx >> 3;
    int k8  = (idx & 7) << 3;
    uint4 raw = make_uint4(0, 0, 0, 0);
    if (r0 + row < N) raw = *(const uint4*)(heb + (size_t)(r0 + row) * 64 + k8);
    xs[k8 + 0][row] = bf2f(raw.x & 0xffff); xs[k8 + 1][row] = bf2f(raw.x >> 16);
    xs[k8 + 2][row] = bf2f(raw.y & 0xffff); xs[k8 + 3][row] = bf2f(raw.y >> 16);
    xs[k8 + 4][row] = bf2f(raw.z & 0xffff); xs[k8 + 5][row] = bf2f(raw.z >> 16);
    xs[k8 + 6][row] = bf2f(raw.w & 0xffff); xs[k8 + 7][row] = bf2f(raw.w >> 16);
  }
  for (int idx = t; idx < 640; idx += 320) {
    int k  = idx / 10;
    int c4 = (idx % 10) << 2;
    *(float4*)(&ws[k][c4]) = *(const float4*)(W2 + k * 40 + c4);
  }
  __syncthreads();
  float acc[4][4] = {};
#pragma unroll 8
  for (int k = 0; k < 64; ++k) {
    float4 xa = *(const float4*)(&xs[k][ty << 2]);
    float4 wb = *(const float4*)(&ws[k][tx << 2]);
    float xv[4] = {xa.x, xa.y, xa.z, xa.w};
    float wv[4] = {wb.x, wb.y, wb.z, wb.w};
#pragma unroll
    for (int i = 0; i < 4; ++i)
#pragma unroll
      for (int j = 0; j < 4; ++j) acc[i][j] = fmaf(xv[i], wv[j], acc[i][j]);
  }
#pragma unroll
  for (int i = 0; i < 4; ++i) {
    int r = r0 + (ty << 2) + i;
    if (r < N) {
      ushort4 o;
      o.x = f2bf(acc[i][0]); o.y = f2bf(acc[i][1]);
      o.z = f2bf(acc[i][2]); o.w = f2bf(acc[i][3]);
      *(ushort4*)(h2b + (size_t)r * 40 + (tx << 2)) = o;
    }
  }
}

// ---------------- layer-2 aggregation + log_softmax (16-deep) ----------------
__global__ __launch_bounds__(256) void agg2_kernel(
    const int* __restrict__ rbeg, const int* __restrict__ rend,
    const int* __restrict__ col,
    const float* __restrict__ s2s, const float* __restrict__ s2d,
    const unsigned short* __restrict__ h2b, const float* __restrict__ b2,
    float* __restrict__ out, int N) {
  int wv = threadIdx.x >> 6;
  int l  = threadIdx.x & 63;
  int n  = blockIdx.x * 4 + wv;
  if (n >= N) return;
  const int q = l >> 3;
  const bool act = (l < 40);
  const unsigned lc = act ? (unsigned)l : 0u;
  const float sdv = s2d[n];
  const int beg = __builtin_amdgcn_readfirstlane(rbeg[n]);
  const int end = __builtin_amdgcn_readfirstlane(rend[n]);
  float z = 0.f, acc = 0.f;
  int e = beg;
  if (((end - beg) >> 3) & 1) {
    int4 ia = *(const int4*)(col + e);
    int4 ib = *(const int4*)(col + e + 4);
    int myidx = col[e + q];
    float pv = s2s[myidx];
    float tt = pv + sdv;
    tt = fmaxf(tt, 0.2f * tt);
    float w = __expf(tt);
    z += w;
    int idxs[8] = {ia.x, ia.y, ia.z, ia.w, ib.x, ib.y, ib.z, ib.w};
#pragma unroll
    for (int j = 0; j < 8; ++j) {
      float wj = __shfl(w, j * 8, 64);
      unsigned short g = h2b[(unsigned)idxs[j] * 40u + lc];
      acc = fmaf(wj, bf2f(g), acc);
    }
    e += 8;
  }
  for (; e < end; e += 16) {
    int4 ia = *(const int4*)(col + e);
    int4 ib = *(const int4*)(col + e + 4);
    int4 ic = *(const int4*)(col + e + 8);
    int4 id = *(const int4*)(col + e + 12);
    int my0 = col[e + q];
    int my1 = col[e + 8 + q];
    float pv0 = s2s[my0];
    float pv1 = s2s[my1];
    int idxs[16] = {ia.x, ia.y, ia.z, ia.w, ib.x, ib.y, ib.z, ib.w,
                    ic.x, ic.y, ic.z, ic.w, id.x, id.y, id.z, id.w};
    unsigned short gg[16];
#pragma unroll
    for (int j = 0; j < 16; ++j) gg[j] = h2b[(unsigned)idxs[j] * 40u + lc];
    float t0 = pv0 + sdv; t0 = fmaxf(t0, 0.2f * t0); float w0 = __expf(t0);
    float t1 = pv1 + sdv; t1 = fmaxf(t1, 0.2f * t1); float w1 = __expf(t1);
    z += w0 + w1;
#pragma unroll
    for (int j = 0; j < 8; ++j) {
      float wj = __shfl(w0, j * 8, 64);
      acc = fmaf(wj, bf2f(gg[j]), acc);
    }
#pragma unroll
    for (int j = 0; j < 8; ++j) {
      float wj = __shfl(w1, j * 8, 64);
      acc = fmaf(wj, bf2f(gg[8 + j]), acc);
    }
  }
  z += __shfl_xor(z, 8); z += __shfl_xor(z, 16); z += __shfl_xor(z, 32);  // all lanes: Z
  float v = act ? (acc / (z + 1e-16f) + b2[l]) : -1e30f;
  float m = v;
  for (int off = 32; off > 0; off >>= 1) m = fmaxf(m, __shfl_xor(m, off));
  float ex = act ? __expf(v - m) : 0.f;
  float s = ex;
  for (int off = 32; off > 0; off >>= 1) s += __shfl_xor(s, off);
  if (act) out[(size_t)n * 40 + l] = v - m - logf(s);
}

// ---------------- launch -----------------------------------------------------
extern "C" void kernel_launch(void* const* d_in, const int* in_sizes, int n_in,
                              void* d_out, int out_size, void* d_ws, size_t ws_size,
                              hipStream_t stream) {
  const float* x   = (const float*)d_in[0];
  const int*   ei  = (const int*)d_in[1];
  const float* W1  = (const float*)d_in[2];
  const float* a1s = (const float*)d_in[3];
  const float* a1d = (const float*)d_in[4];
  const float* b1  = (const float*)d_in[5];
  const float* W2  = (const float*)d_in[6];
  const float* a2s = (const float*)d_in[7];
  const float* a2d = (const float*)d_in[8];
  const float* b2  = (const float*)d_in[9];
  float* out = (float*)d_out;
  (void)n_in; (void)out_size; (void)ws_size;

  const int NN = in_sizes[0] / 256;
  const int E  = in_sizes[1] / 2;
  const int NB = (NN + KNODES - 1) >> BK;
  const int* esrc = ei;
  const int* edst = ei + E;

  // fixed per-bucket payload capacity: mean + 31% + 512 (>>30 sigma for iid edges)
  int capP = (E + NB - 1) / NB;
  capP += capP / 4 + capP / 16 + 512;
  capP = (capP + 15) & ~15;

  char* p = (char*)d_ws;
  auto alloc = [&](size_t bytes) -> char* {
    char* q = p;
    p += (bytes + 255) & ~(size_t)255;
    return q;
  };
  unsigned short* h1b   = (unsigned short*)alloc((size_t)(NN + 1) * 64 * 2);
  unsigned short* helub = (unsigned short*)alloc((size_t)NN * 64 * 2);
  unsigned short* h2b   = (unsigned short*)alloc((size_t)(NN + 1) * 40 * 2);
  float* s1s  = (float*)alloc((size_t)(NN + 1) * 8 * 4);
  float* s1d  = (float*)alloc((size_t)NN * 8 * 4);
  float* s2s  = (float*)alloc((size_t)(NN + 1) * 4);
  float* s2d  = (float*)alloc((size_t)NN * 4);
  int*   rbeg = (int*)alloc((size_t)NN * 4);
  int*   rend = (int*)alloc((size_t)NN * 4);
  int*   bpos = (int*)alloc(MAXNB * 4);
  unsigned int* payload = (unsigned int*)alloc((size_t)NB * capP * 4);
  int*   col  = (int*)alloc((size_t)NB * (capP + 8 * KNODES) * 4);
  float* vas  = (float*)alloc(64 * 4);
  float* vad  = (float*)alloc(64 * 4);
  unsigned short* w1hi = (unsigned short*)alloc(32 * 64 * 8 * 2);
  unsigned short* w1lo = (unsigned short*)alloc(32 * 64 * 8 * 2);

  // 1) prep (bpos init, W1 frags, va, sentinels)
  prep_kernel<<<34, 256, 0, stream>>>(W1, W2, a2s, a2d, w1hi, w1lo, vas, vad,
                                      h1b, h2b, s1s, s2s, bpos, capP, NN);
  // 2-3) CSR build
  bin_kernel<<<(E + 4095) / 4096, 256, 0, stream>>>(esrc, edst, bpos, payload, E, NB, capP);
  fill2_kernel<<<NB, 1024, 0, stream>>>(payload, bpos, col, rbeg, rend, capP, NN);
  // 4-8) dense math + aggregations
  gemm1_mfma_kernel<<<(NN + 63) / 64, 256, 0, stream>>>(x, w1hi, w1lo, h1b, NN);
  s1_kernel<<<(NN * 8 + 255) / 256, 256, 0, stream>>>(h1b, a1s, a1d, s1s, s1d, NN * 8);
  agg1_kernel<<<(NN + 3) / 4, 256, 0, stream>>>(rbeg, rend, col, s1s, s1d, h1b, b1,
                                                vas, vad, helub, s2s, s2d, NN);
  gemm2_kernel<<<(NN + 127) / 128, 320, 0, stream>>>(helub, W2, h2b, NN);
  agg2_kernel<<<(NN + 3) / 4, 256, 0, stream>>>(rbeg, rend, col, s2s, s2d, h2b, b2, out, NN);
}